// Round 2
// baseline (257.957 us; speedup 1.0000x reference)
//
#include <hip/hip_runtime.h>

typedef __attribute__((ext_vector_type(4))) float f32x4;
typedef __attribute__((ext_vector_type(8))) short short8;
typedef __attribute__((ext_vector_type(4))) short short4v;
typedef __attribute__((ext_vector_type(4))) unsigned short ushort4v;
typedef __attribute__((ext_vector_type(8))) unsigned short ushort8v;

#define B_ROWS 4096
#define I_DIM  1024
#define O_DIM  1024
#define C_DIM  128
#define E_NUM  8

// ws layout: [0] int flag | [1024] float g[4096*8] | [+128KB] u16 Wt[8*1024*1024]
//            | [+16MB] f32 partials[KS][4096*1024]

__device__ __forceinline__ float bfu2f(unsigned short u) {
  return __uint_as_float(((unsigned int)u) << 16);
}
__device__ __forceinline__ unsigned short f2bf(float f) {
  unsigned int u = __float_as_uint(f);
  unsigned int r = (u + 0x7FFFu + ((u >> 16) & 1u)) >> 16;  // RNE
  return (unsigned short)r;
}
__device__ __forceinline__ float ldany(const void* p, size_t idx, bool isbf) {
  return isbf ? bfu2f(((const unsigned short*)p)[idx]) : ((const float*)p)[idx];
}
__device__ __forceinline__ void gload_lds16(const void* g, void* lds) {
  __builtin_amdgcn_global_load_lds(
      (const __attribute__((address_space(1))) void*)g,
      (__attribute__((address_space(3))) void*)lds, 16, 0, 0);
}

// ---------------- dtype detect: bf16 storage -> flag=1, f32 -> flag=0 -------
__global__ void k_detect(const unsigned short* __restrict__ x, int* __restrict__ flag) {
  if (blockIdx.x == 0 && threadIdx.x == 0) {
    int sane = 0;
    for (int k = 0; k < 128; ++k) {
      const unsigned short v = x[k];
      const int ex = (v >> 7) & 0xFF;
      if (v == 0 || (ex >= 100 && ex <= 132)) ++sane;
    }
    *flag = (sane >= 120) ? 1 : 0;
  }
}

// ---------------- gating MLP + softmax, one thread per row ------------------
__global__ __launch_bounds__(256) void k_gating(
    const void* __restrict__ cond, const void* __restrict__ w1,
    const void* __restrict__ b1, const void* __restrict__ w2,
    const void* __restrict__ b2, const int* __restrict__ flag,
    float* __restrict__ g)
{
  __shared__ float s_w1[C_DIM * 32];
  __shared__ float s_w2[32 * E_NUM];
  __shared__ float s_b1[32];
  __shared__ float s_b2[E_NUM];
  const bool isbf = (*flag != 0);
  for (int t = threadIdx.x; t < C_DIM * 32; t += 256) s_w1[t] = ldany(w1, t, isbf);
  if (threadIdx.x < 32 * E_NUM) s_w2[threadIdx.x] = ldany(w2, threadIdx.x, isbf);
  if (threadIdx.x < 32) s_b1[threadIdx.x] = ldany(b1, threadIdx.x, isbf);
  if (threadIdx.x < E_NUM) s_b2[threadIdx.x] = ldany(b2, threadIdx.x, isbf);
  __syncthreads();
  const int b = blockIdx.x * 256 + threadIdx.x;
  float h[32];
#pragma unroll
  for (int j = 0; j < 32; ++j) h[j] = s_b1[j];
  for (int i = 0; i < C_DIM; i += 8) {
    float c[8];
    if (isbf) {
      const unsigned short* cu = (const unsigned short*)cond;
      ushort8v v = *(const ushort8v*)&cu[(size_t)b * C_DIM + i];
#pragma unroll
      for (int q = 0; q < 8; ++q) c[q] = bfu2f(v[q]);
    } else {
      const float* cf = (const float*)cond;
      f32x4 v0 = *(const f32x4*)&cf[(size_t)b * C_DIM + i];
      f32x4 v1 = *(const f32x4*)&cf[(size_t)b * C_DIM + i + 4];
#pragma unroll
      for (int q = 0; q < 4; ++q) { c[q] = v0[q]; c[q + 4] = v1[q]; }
    }
#pragma unroll
    for (int q = 0; q < 8; ++q)
#pragma unroll
      for (int j = 0; j < 32; ++j)
        h[j] = fmaf(c[q], s_w1[(i + q) * 32 + j], h[j]);
  }
#pragma unroll
  for (int j = 0; j < 32; ++j) h[j] = fmaxf(h[j], 0.f);
  float lg[E_NUM];
#pragma unroll
  for (int e = 0; e < E_NUM; ++e) lg[e] = s_b2[e];
#pragma unroll
  for (int j = 0; j < 32; ++j)
#pragma unroll
    for (int e = 0; e < E_NUM; ++e)
      lg[e] = fmaf(h[j], s_w2[j * E_NUM + e], lg[e]);
  float mx = lg[0];
#pragma unroll
  for (int e = 1; e < E_NUM; ++e) mx = fmaxf(mx, lg[e]);
  float s = 0.f;
#pragma unroll
  for (int e = 0; e < E_NUM; ++e) { lg[e] = expf(lg[e] - mx); s += lg[e]; }
  const float inv = 1.f / s;
#pragma unroll
  for (int e = 0; e < E_NUM; ++e) g[(size_t)b * E_NUM + e] = lg[e] * inv;
}

// ---------------- W[e][i][o] -> Wt[e][o][i] (bf16), 64x64 tiles -------------
__global__ __launch_bounds__(256) void k_transpose_w(
    const void* __restrict__ wv, const int* __restrict__ flag,
    unsigned short* __restrict__ wt)
{
  __shared__ float tile[64][65];
  const bool isbf = (*flag != 0);
  const int bid = blockIdx.x;
  const int e = bid >> 8;
  const int t = bid & 255;
  const int i0 = (t >> 4) << 6;
  const int o0 = (t & 15) << 6;
  const size_t base = (size_t)e << 20;
  const int tid = threadIdx.x;
  const int r = tid >> 2;
  const int sub = tid & 3;
  if (isbf) {
    const unsigned short* wu = (const unsigned short*)wv;
#pragma unroll
    for (int q = 0; q < 4; ++q) {
      const int c = sub * 16 + q * 4;
      ushort4v v = *(const ushort4v*)&wu[base + (size_t)(i0 + r) * O_DIM + o0 + c];
#pragma unroll
      for (int j = 0; j < 4; ++j) tile[r][c + j] = bfu2f(v[j]);
    }
  } else {
    const float* wf = (const float*)wv;
#pragma unroll
    for (int q = 0; q < 4; ++q) {
      const int c = sub * 16 + q * 4;
      f32x4 v = *(const f32x4*)&wf[base + (size_t)(i0 + r) * O_DIM + o0 + c];
#pragma unroll
      for (int j = 0; j < 4; ++j) tile[r][c + j] = v[j];
    }
  }
  __syncthreads();
  const int oc = tid >> 2;
#pragma unroll
  for (int q = 0; q < 4; ++q) {
    const int il = sub * 16 + q * 4;
    ushort4v p;
#pragma unroll
    for (int j = 0; j < 4; ++j) p[j] = f2bf(tile[il + j][oc]);
    *(ushort4v*)&wt[base + (size_t)(o0 + oc) * I_DIM + i0 + il] = p;
  }
}

// ---------------- main GEMM with expert-split-K -----------------------------
// 128x128 tile, BK=64, 4 waves (2x2) each 64x64 (4x4 frags). Grid =
// KS * 32 * 8. Each block handles EPB=8/KS experts via rescale-chain:
// acc *= gc[e-1]/gc[e] at expert boundaries, final *= gc[elast] ->
// acc = sum_e g_e * (x@W_e) with no second accumulator. f32 partials to ws.
#define BM 128
#define BN 128
#define BK 64
#define MT (B_ROWS / BM)   // 32
#define NT (O_DIM / BN)    // 8

__global__ __launch_bounds__(256, 3) void k_moe_gemm(
    const void* __restrict__ xv, const unsigned short* __restrict__ wt,
    const float* __restrict__ g, const int* __restrict__ flag,
    float* __restrict__ pbuf, int KS, int EPB)
{
  __shared__ unsigned short As[BM * BK];   // 16KB [row][k]
  __shared__ unsigned short Bs[BN * BK];   // 16KB [col][k]
  __shared__ float gsh[BM * E_NUM];        // 4KB

  const int tid  = threadIdx.x;
  const int lane = tid & 63;
  const int wid  = tid >> 6;
  const int wr   = wid >> 1;
  const int wc   = wid & 1;

  // bijective XCD swizzle (nwg = KS*256, % 8 == 0)
  const int nwg = KS * MT * NT;
  const int cpx = nwg >> 3;
  const int wg  = (blockIdx.x & 7) * cpx + (blockIdx.x >> 3);
  const int ks  = wg / (MT * NT);
  const int t2  = wg - ks * (MT * NT);
  const int mt  = t2 >> 3;
  const int nt  = t2 & 7;
  const int row0 = mt * BM;
  const int col0 = nt * BN;
  const bool isbf = (*flag != 0);

  for (int i = tid; i < BM * E_NUM; i += 256) gsh[i] = g[row0 * E_NUM + i];

  f32x4 acc[4][4];
#pragma unroll
  for (int m = 0; m < 4; ++m)
#pragma unroll
    for (int n = 0; n < 4; ++n)
#pragma unroll
      for (int r2 = 0; r2 < 4; ++r2) acc[m][n][r2] = 0.f;

  const int r16  = lane & 15;
  const int krow = lane >> 4;
  const int e0   = ks * EPB;

  // staging geometry: 16 chunks of 1KB each for A and B; chunk = wid*4+q
  const int srow = lane >> 3;          // row-within-chunk
  const int sko  = (lane & 7) << 3;    // bf16 k-offset within row

  for (int j = 0; j < EPB; ++j) {
    const int e = e0 + j;
    if (j > 0) {
#pragma unroll
      for (int m = 0; m < 4; ++m) {
        const int rb = wr * 64 + m * 16 + krow * 4;
        float ra[4];
#pragma unroll
        for (int r2 = 0; r2 < 4; ++r2) {
          const float num = fmaxf(gsh[(rb + r2) * E_NUM + e - 1], 1e-30f);
          const float den = fmaxf(gsh[(rb + r2) * E_NUM + e], 1e-30f);
          ra[r2] = num / den;
        }
#pragma unroll
        for (int n = 0; n < 4; ++n)
#pragma unroll
          for (int r2 = 0; r2 < 4; ++r2) acc[m][n][r2] *= ra[r2];
      }
    }
    const size_t wb = (size_t)e << 20;
    for (int kt = 0; kt < I_DIM / BK; ++kt) {
      const int i0 = kt * BK;
      __syncthreads();
      // stage B tile
#pragma unroll
      for (int q = 0; q < 4; ++q) {
        const int chunk = wid * 4 + q;
        const int col = (chunk << 3) + srow;
        gload_lds16(wt + wb + ((size_t)(col0 + col) << 10) + i0 + sko,
                    (char*)Bs + (chunk << 10));
      }
      // stage A tile
      if (isbf) {
        const unsigned short* xu = (const unsigned short*)xv;
#pragma unroll
        for (int q = 0; q < 4; ++q) {
          const int chunk = wid * 4 + q;
          const int row = (chunk << 3) + srow;
          gload_lds16(xu + (size_t)(row0 + row) * I_DIM + i0 + sko,
                      (char*)As + (chunk << 10));
        }
      } else {
        const float* xf = (const float*)xv;
        const int r  = tid >> 1;
        const int k0 = (tid & 1) << 5;
#pragma unroll
        for (int q = 0; q < 8; ++q) {
          f32x4 v = *(const f32x4*)&xf[(size_t)(row0 + r) * I_DIM + i0 + k0 + q * 4];
          short4v p;
#pragma unroll
          for (int jj = 0; jj < 4; ++jj) p[jj] = (short)f2bf(v[jj]);
          *(short4v*)&As[r * BK + k0 + q * 4] = p;
        }
      }
      __syncthreads();
      // compute: 2 k-steps of 32, 16 MFMAs each
#pragma unroll
      for (int ks2 = 0; ks2 < 2; ++ks2) {
        const int kof = ks2 * 32 + krow * 8;
        short8 a[4], b[4];
#pragma unroll
        for (int m = 0; m < 4; ++m)
          a[m] = *(const short8*)&As[(wr * 64 + m * 16 + r16) * BK + kof];
#pragma unroll
        for (int n = 0; n < 4; ++n)
          b[n] = *(const short8*)&Bs[(wc * 64 + n * 16 + r16) * BK + kof];
#pragma unroll
        for (int m = 0; m < 4; ++m)
#pragma unroll
          for (int n = 0; n < 4; ++n)
            acc[m][n] = __builtin_amdgcn_mfma_f32_16x16x32_bf16(a[m], b[n], acc[m][n], 0, 0, 0);
      }
    }
  }

  // epilogue: final gate scale, write f32 partial
  const int elast = e0 + EPB - 1;
  float* pb = pbuf + ((size_t)ks << 22);
#pragma unroll
  for (int m = 0; m < 4; ++m) {
    const int rb = wr * 64 + m * 16 + krow * 4;
    float gl[4];
#pragma unroll
    for (int r2 = 0; r2 < 4; ++r2)
      gl[r2] = fmaxf(gsh[(rb + r2) * E_NUM + elast], 1e-30f);
#pragma unroll
    for (int n = 0; n < 4; ++n) {
      const int c = col0 + wc * 64 + n * 16 + r16;
#pragma unroll
      for (int r2 = 0; r2 < 4; ++r2)
        pb[(size_t)(row0 + rb + r2) * O_DIM + c] = acc[m][n][r2] * gl[r2];
    }
  }
}

// ---------------- combine: sum partials + bias term, cast -------------------
__global__ __launch_bounds__(256) void k_combine(
    const float* __restrict__ pbuf, const float* __restrict__ g,
    const void* __restrict__ biasv, const int* __restrict__ flag,
    void* __restrict__ outv, int KS)
{
  const int idx = blockIdx.x * 256 + threadIdx.x;
  const int b = idx >> 8;
  const int o = (idx & 255) << 2;
  const bool isbf = (*flag != 0);
  f32x4 s = {0.f, 0.f, 0.f, 0.f};
  for (int ks = 0; ks < KS; ++ks) {
    f32x4 v = *(const f32x4*)&pbuf[((size_t)ks << 22) + (size_t)b * O_DIM + o];
#pragma unroll
    for (int jj = 0; jj < 4; ++jj) s[jj] += v[jj];
  }
  float gr[E_NUM];
#pragma unroll
  for (int e = 0; e < E_NUM; ++e) gr[e] = g[(size_t)b * E_NUM + e];
#pragma unroll
  for (int e = 0; e < E_NUM; ++e)
#pragma unroll
    for (int jj = 0; jj < 4; ++jj)
      s[jj] += gr[e] * ldany(biasv, (size_t)e * O_DIM + o + jj, isbf);
  if (isbf) {
    ushort4v pk;
#pragma unroll
    for (int jj = 0; jj < 4; ++jj) pk[jj] = f2bf(s[jj]);
    *(ushort4v*)&((unsigned short*)outv)[(size_t)b * O_DIM + o] = pk;
  } else {
    *(f32x4*)&((float*)outv)[(size_t)b * O_DIM + o] = s;
  }
}

extern "C" void kernel_launch(void* const* d_in, const int* in_sizes, int n_in,
                              void* d_out, int out_size, void* d_ws, size_t ws_size,
                              hipStream_t stream) {
  (void)in_sizes; (void)n_in; (void)out_size;
  const void* x    = d_in[0];
  const void* cond = d_in[1];
  const void* w    = d_in[2];
  const void* bias = d_in[3];
  const void* g_w1 = d_in[4];
  const void* g_b1 = d_in[5];
  const void* g_w2 = d_in[6];
  const void* g_b2 = d_in[7];

  const size_t goff   = 1024;
  const size_t gbytes = (size_t)B_ROWS * E_NUM * 4;         // 128KB
  const size_t wtoff  = goff + gbytes;
  const size_t wtby   = (size_t)E_NUM * I_DIM * O_DIM * 2;  // 16MB
  const size_t poff   = wtoff + wtby;
  const size_t slab   = (size_t)B_ROWS * O_DIM * 4;         // 16MB

  int KS = 4;
  while (KS > 1 && poff + (size_t)KS * slab > ws_size) KS >>= 1;
  const int EPB = E_NUM / KS;

  int*   flag = (int*)d_ws;
  float* g    = (float*)((char*)d_ws + goff);
  unsigned short* wt = (unsigned short*)((char*)d_ws + wtoff);
  float* pbuf = (float*)((char*)d_ws + poff);

  k_detect<<<1, 64, 0, stream>>>((const unsigned short*)x, flag);
  k_gating<<<B_ROWS / 256, 256, 0, stream>>>(cond, g_w1, g_b1, g_w2, g_b2, flag, g);
  k_transpose_w<<<E_NUM * 256, 256, 0, stream>>>(w, flag, wt);
  k_moe_gemm<<<KS * MT * NT, 256, 0, stream>>>(x, wt, g, flag, pbuf, KS, EPB);
  k_combine<<<B_ROWS * O_DIM / 4 / 256, 256, 0, stream>>>(pbuf, g, bias, flag, d_out, KS);
}

// Round 3
// 173.160 us; speedup vs baseline: 1.4897x; 1.4897x over previous
//
#include <hip/hip_runtime.h>

typedef __attribute__((ext_vector_type(4))) float f32x4;
typedef __attribute__((ext_vector_type(8))) short short8;
typedef __attribute__((ext_vector_type(4))) short short4v;
typedef __attribute__((ext_vector_type(4))) unsigned short ushort4v;
typedef __attribute__((ext_vector_type(8))) unsigned short ushort8v;

#define B_ROWS 4096
#define I_DIM  1024
#define O_DIM  1024
#define C_DIM  128
#define E_NUM  8

__device__ __forceinline__ float bfu2f(unsigned short u) {
  return __uint_as_float(((unsigned int)u) << 16);
}
__device__ __forceinline__ unsigned short f2bf(float f) {
  unsigned int u = __float_as_uint(f);
  unsigned int r = (u + 0x7FFFu + ((u >> 16) & 1u)) >> 16;  // RNE
  return (unsigned short)r;
}
__device__ __forceinline__ float ldany(const void* p, size_t idx, bool isbf) {
  return isbf ? bfu2f(((const unsigned short*)p)[idx]) : ((const float*)p)[idx];
}
__device__ __forceinline__ void gload_lds16(const void* g, void* lds) {
  __builtin_amdgcn_global_load_lds(
      (const __attribute__((address_space(1))) void*)g,
      (__attribute__((address_space(3))) void*)lds, 16, 0, 0);
}

// ---------------- dtype detect: bf16 storage -> flag=1, f32 -> flag=0 -------
__global__ void k_detect(const unsigned short* __restrict__ x, int* __restrict__ flag) {
  if (blockIdx.x == 0 && threadIdx.x == 0) {
    int sane = 0;
    for (int k = 0; k < 128; ++k) {
      const unsigned short v = x[k];
      const int ex = (v >> 7) & 0xFF;
      if (v == 0 || (ex >= 100 && ex <= 132)) ++sane;
    }
    *flag = (sane >= 120) ? 1 : 0;
  }
}

// ---------------- x -> bf16 copy/cast (uniform GEMM input) ------------------
__global__ __launch_bounds__(256) void k_cast_x(
    const void* __restrict__ xv, const int* __restrict__ flag,
    unsigned short* __restrict__ xb)
{
  const bool isbf = (*flag != 0);
  const size_t i = ((size_t)blockIdx.x * 256 + threadIdx.x) * 8;
  if (isbf) {
    *(ushort8v*)&xb[i] = *(const ushort8v*)&((const unsigned short*)xv)[i];
  } else {
    const float* xf = (const float*)xv;
    f32x4 a = *(const f32x4*)&xf[i];
    f32x4 b = *(const f32x4*)&xf[i + 4];
    ushort8v p;
#pragma unroll
    for (int j = 0; j < 4; ++j) { p[j] = f2bf(a[j]); p[j + 4] = f2bf(b[j]); }
    *(ushort8v*)&xb[i] = p;
  }
}

// ---------------- gating MLP + softmax, one thread per row ------------------
__global__ __launch_bounds__(256) void k_gating(
    const void* __restrict__ cond, const void* __restrict__ w1,
    const void* __restrict__ b1, const void* __restrict__ w2,
    const void* __restrict__ b2, const int* __restrict__ flag,
    float* __restrict__ g)
{
  __shared__ float s_w1[C_DIM * 32];
  __shared__ float s_w2[32 * E_NUM];
  __shared__ float s_b1[32];
  __shared__ float s_b2[E_NUM];
  const bool isbf = (*flag != 0);
  for (int t = threadIdx.x; t < C_DIM * 32; t += 256) s_w1[t] = ldany(w1, t, isbf);
  if (threadIdx.x < 32 * E_NUM) s_w2[threadIdx.x] = ldany(w2, threadIdx.x, isbf);
  if (threadIdx.x < 32) s_b1[threadIdx.x] = ldany(b1, threadIdx.x, isbf);
  if (threadIdx.x < E_NUM) s_b2[threadIdx.x] = ldany(b2, threadIdx.x, isbf);
  __syncthreads();
  const int b = blockIdx.x * 256 + threadIdx.x;
  float h[32];
#pragma unroll
  for (int j = 0; j < 32; ++j) h[j] = s_b1[j];
  for (int i = 0; i < C_DIM; i += 8) {
    float c[8];
    if (isbf) {
      const unsigned short* cu = (const unsigned short*)cond;
      ushort8v v = *(const ushort8v*)&cu[(size_t)b * C_DIM + i];
#pragma unroll
      for (int q = 0; q < 8; ++q) c[q] = bfu2f(v[q]);
    } else {
      const float* cf = (const float*)cond;
      f32x4 v0 = *(const f32x4*)&cf[(size_t)b * C_DIM + i];
      f32x4 v1 = *(const f32x4*)&cf[(size_t)b * C_DIM + i + 4];
#pragma unroll
      for (int q = 0; q < 4; ++q) { c[q] = v0[q]; c[q + 4] = v1[q]; }
    }
#pragma unroll
    for (int q = 0; q < 8; ++q)
#pragma unroll
      for (int j = 0; j < 32; ++j)
        h[j] = fmaf(c[q], s_w1[(i + q) * 32 + j], h[j]);
  }
#pragma unroll
  for (int j = 0; j < 32; ++j) h[j] = fmaxf(h[j], 0.f);
  float lg[E_NUM];
#pragma unroll
  for (int e = 0; e < E_NUM; ++e) lg[e] = s_b2[e];
#pragma unroll
  for (int j = 0; j < 32; ++j)
#pragma unroll
    for (int e = 0; e < E_NUM; ++e)
      lg[e] = fmaf(h[j], s_w2[j * E_NUM + e], lg[e]);
  float mx = lg[0];
#pragma unroll
  for (int e = 1; e < E_NUM; ++e) mx = fmaxf(mx, lg[e]);
  float s = 0.f;
#pragma unroll
  for (int e = 0; e < E_NUM; ++e) { lg[e] = expf(lg[e] - mx); s += lg[e]; }
  const float inv = 1.f / s;
#pragma unroll
  for (int e = 0; e < E_NUM; ++e) g[(size_t)b * E_NUM + e] = lg[e] * inv;
}

// ---------------- W[e][i][o] -> Wt[e][o][i] (bf16), 64x64 tiles -------------
__global__ __launch_bounds__(256) void k_transpose_w(
    const void* __restrict__ wv, const int* __restrict__ flag,
    unsigned short* __restrict__ wt)
{
  __shared__ float tile[64][65];
  const bool isbf = (*flag != 0);
  const int bid = blockIdx.x;
  const int e = bid >> 8;
  const int t = bid & 255;
  const int i0 = (t >> 4) << 6;
  const int o0 = (t & 15) << 6;
  const size_t base = (size_t)e << 20;
  const int tid = threadIdx.x;
  const int r = tid >> 2;
  const int sub = tid & 3;
  if (isbf) {
    const unsigned short* wu = (const unsigned short*)wv;
#pragma unroll
    for (int q = 0; q < 4; ++q) {
      const int c = sub * 16 + q * 4;
      ushort4v v = *(const ushort4v*)&wu[base + (size_t)(i0 + r) * O_DIM + o0 + c];
#pragma unroll
      for (int j = 0; j < 4; ++j) tile[r][c + j] = bfu2f(v[j]);
    }
  } else {
    const float* wf = (const float*)wv;
#pragma unroll
    for (int q = 0; q < 4; ++q) {
      const int c = sub * 16 + q * 4;
      f32x4 v = *(const f32x4*)&wf[base + (size_t)(i0 + r) * O_DIM + o0 + c];
#pragma unroll
      for (int j = 0; j < 4; ++j) tile[r][c + j] = v[j];
    }
  }
  __syncthreads();
  const int oc = tid >> 2;
#pragma unroll
  for (int q = 0; q < 4; ++q) {
    const int il = sub * 16 + q * 4;
    ushort4v p;
#pragma unroll
    for (int j = 0; j < 4; ++j) p[j] = f2bf(tile[il + j][oc]);
    *(ushort4v*)&wt[base + (size_t)(o0 + oc) * I_DIM + i0 + il] = p;
  }
}

// ---------------- main GEMM: phase-interleaved, counted-vmcnt ring-3 --------
// 256x256 tile, BK=32, 8 waves (2M x 4N) each 128x64. Ring of 3 LDS K-tile
// slots: iteration t computes tile t (slot t%3) in 2 phases (16 MFMA each,
// setprio-wrapped, 2 barriers/phase), stages tile t+2 into slot (t+2)%3
// (ph0: A, ph1: B), vmcnt(4) once per tile (never 0). Expert-split-K (KS
// blocks over experts) with gate rescale-chain at expert boundaries.
#define BM 256
#define BN 256
#define BK 32
#define MT (B_ROWS / BM)   // 16
#define NT (O_DIM / BN)    // 4

__global__ __launch_bounds__(512, 2) void k_moe_gemm(
    const unsigned short* __restrict__ xb, const unsigned short* __restrict__ wt,
    const float* __restrict__ g, float* __restrict__ pbuf, int EPB)
{
  __shared__ unsigned short As[3][BM * BK];  // 3 x 16KB, [row][k] 64B rows
  __shared__ unsigned short Bs[3][BN * BK];  // 3 x 16KB, [col][k]
  __shared__ float gsh[BM * E_NUM];          // 8KB

  const int tid  = threadIdx.x;
  const int lane = tid & 63;
  const int w    = tid >> 6;      // wave 0..7
  const int wr   = w >> 2;        // 0..1  (128 rows)
  const int wc   = w & 3;         // 0..3  (64 cols)

  // bijective XCD swizzle (nwg = KS*64, % 8 == 0)
  const int nwg = gridDim.x;
  const int cpx = nwg >> 3;
  const int wg  = ((int)blockIdx.x & 7) * cpx + ((int)blockIdx.x >> 3);
  const int ks  = wg >> 6;            // split-K slice
  const int t2  = wg & 63;
  const int mt  = t2 >> 2;
  const int nt  = t2 & 3;
  const int row0 = mt * BM;
  const int col0 = nt * BN;
  const int NKT  = EPB * (I_DIM / BK);   // tiles per block
  const int e0   = ks * EPB;

  for (int i = tid; i < BM * E_NUM; i += 512) gsh[i] = g[row0 * E_NUM + i];

  // staging geometry: chunk j of wave w covers 16 rows x 32 k (1KB); lane
  // l -> row lr = l>>2, 16B slot ls = l&3. LDS linear, no swizzle (64B rows
  // distribute evenly over banks).
  const int lr = lane >> 2;
  const int ls = lane & 3;
  const unsigned short* aS0 = xb + (size_t)(row0 + w * 32 + lr) * I_DIM + ls * 8;
  const unsigned short* aS1 = aS0 + (size_t)16 * I_DIM;
  const unsigned short* bS0 = wt + (size_t)(col0 + w * 32 + lr) * I_DIM + ls * 8;
  const unsigned short* bS1 = bS0 + (size_t)16 * I_DIM;
  const int dA0 = (w * 2 + 0) * 512, dA1 = (w * 2 + 1) * 512;

#define STAGE_A(nsl, koff) do { \
    gload_lds16(aS0 + (koff), &As[nsl][dA0]); \
    gload_lds16(aS1 + (koff), &As[nsl][dA1]); } while (0)
#define STAGE_B(nsl, ebase, koff) do { \
    gload_lds16(bS0 + (ebase) + (koff), &Bs[nsl][dA0]); \
    gload_lds16(bS1 + (ebase) + (koff), &Bs[nsl][dA1]); } while (0)

  // fragment read geometry
  const int r16  = lane & 15;
  const int krow = lane >> 4;
  const int aro  = (wr * 128 + r16) * BK + krow * 8;  // + m*512
  const int bro  = (wc * 64 + r16) * BK + krow * 8;   // + n*512

  f32x4 acc[8][4];
#pragma unroll
  for (int m = 0; m < 8; ++m)
#pragma unroll
    for (int n = 0; n < 4; ++n)
#pragma unroll
      for (int r2 = 0; r2 < 4; ++r2) acc[m][n][r2] = 0.f;

  // prologue: stage tiles 0,1 into slots 0,1 (order: A0,B0,A1,B1)
  STAGE_A(0, 0);
  STAGE_B(0, (size_t)e0 << 20, 0);
  STAGE_A(1, BK);
  STAGE_B(1, (size_t)e0 << 20, BK);
  asm volatile("s_waitcnt vmcnt(4) lgkmcnt(0)" ::: "memory");
  __builtin_amdgcn_sched_barrier(0);
  __builtin_amdgcn_s_barrier();

  int sl = 0;
  for (int t = 0; t < NKT; ++t) {
    const int nsl = (sl == 0) ? 2 : sl - 1;          // (t+2)%3
    const unsigned short* Asl = As[sl];
    const unsigned short* Bsl = Bs[sl];

    // expert boundary: acc *= g[e-1]/g[e]
    if (t > 0 && (t & 31) == 0) {
      const int en = e0 + (t >> 5);
#pragma unroll
      for (int m = 0; m < 8; ++m) {
        const int rowl = wr * 128 + m * 16 + krow * 4;
        float ra[4];
#pragma unroll
        for (int r2 = 0; r2 < 4; ++r2)
          ra[r2] = fmaxf(gsh[(rowl + r2) * E_NUM + en - 1], 1e-30f) /
                   fmaxf(gsh[(rowl + r2) * E_NUM + en], 1e-30f);
#pragma unroll
        for (int n = 0; n < 4; ++n)
#pragma unroll
          for (int r2 = 0; r2 < 4; ++r2) acc[m][n][r2] *= ra[r2];
      }
    }

    const int kst  = (t + 2) & (NKT - 1);
    const size_t eb = (size_t)(e0 + (kst >> 5)) << 20;
    const int koff = (kst & 31) * BK;

    short8 bf[4], af[4];
    // ---- phase 0: read B(n0-3) + A(m0-3), stage A(t+2), MFMA m0-3 ----
#pragma unroll
    for (int n = 0; n < 4; ++n) bf[n] = *(const short8*)&Bsl[bro + n * 512];
#pragma unroll
    for (int m = 0; m < 4; ++m) af[m] = *(const short8*)&Asl[aro + m * 512];
    STAGE_A(nsl, koff);
    __builtin_amdgcn_sched_barrier(0);
    __builtin_amdgcn_s_barrier();
    asm volatile("s_waitcnt lgkmcnt(0)" ::: "memory");
    __builtin_amdgcn_sched_barrier(0);
    __builtin_amdgcn_s_setprio(1);
#pragma unroll
    for (int m = 0; m < 4; ++m)
#pragma unroll
      for (int n = 0; n < 4; ++n)
        acc[m][n] = __builtin_amdgcn_mfma_f32_16x16x32_bf16(af[m], bf[n], acc[m][n], 0, 0, 0);
    __builtin_amdgcn_s_setprio(0);
    __builtin_amdgcn_sched_barrier(0);
    __builtin_amdgcn_s_barrier();

    // ---- phase 1: read A(m4-7), stage B(t+2), vmcnt(4), MFMA m4-7 ----
#pragma unroll
    for (int m = 0; m < 4; ++m) af[m] = *(const short8*)&Asl[aro + (m + 4) * 512];
    STAGE_B(nsl, eb, koff);
    __builtin_amdgcn_sched_barrier(0);
    asm volatile("s_waitcnt vmcnt(4)" ::: "memory");
    __builtin_amdgcn_sched_barrier(0);
    __builtin_amdgcn_s_barrier();
    asm volatile("s_waitcnt lgkmcnt(0)" ::: "memory");
    __builtin_amdgcn_sched_barrier(0);
    __builtin_amdgcn_s_setprio(1);
#pragma unroll
    for (int m = 0; m < 4; ++m)
#pragma unroll
      for (int n = 0; n < 4; ++n)
        acc[m + 4][n] = __builtin_amdgcn_mfma_f32_16x16x32_bf16(af[m], bf[n], acc[m + 4][n], 0, 0, 0);
    __builtin_amdgcn_s_setprio(0);
    __builtin_amdgcn_sched_barrier(0);
    __builtin_amdgcn_s_barrier();

    sl = (sl == 2) ? 0 : sl + 1;
  }
#undef STAGE_A
#undef STAGE_B

  // epilogue: drain wrap stages, final gate scale, write f32 partial
  asm volatile("s_waitcnt vmcnt(0)" ::: "memory");
  const int elast = e0 + EPB - 1;
  float* pb = pbuf + ((size_t)ks << 22);
#pragma unroll
  for (int m = 0; m < 8; ++m) {
    const int rowl = wr * 128 + m * 16 + krow * 4;
    float gl[4];
#pragma unroll
    for (int r2 = 0; r2 < 4; ++r2)
      gl[r2] = fmaxf(gsh[(rowl + r2) * E_NUM + elast], 1e-30f);
#pragma unroll
    for (int n = 0; n < 4; ++n) {
      const int c = col0 + wc * 64 + n * 16 + r16;
#pragma unroll
      for (int r2 = 0; r2 < 4; ++r2)
        pb[(size_t)(row0 + rowl + r2) * O_DIM + c] = acc[m][n][r2] * gl[r2];
    }
  }
}

// ---------------- combine: sum partials + bias term, cast -------------------
__global__ __launch_bounds__(256) void k_combine(
    const float* __restrict__ pbuf, const float* __restrict__ g,
    const void* __restrict__ biasv, const int* __restrict__ flag,
    void* __restrict__ outv, int KS)
{
  const int idx = blockIdx.x * 256 + threadIdx.x;
  const int b = idx >> 8;
  const int o = (idx & 255) << 2;
  const bool isbf = (*flag != 0);
  f32x4 s = {0.f, 0.f, 0.f, 0.f};
  for (int ks = 0; ks < KS; ++ks) {
    f32x4 v = *(const f32x4*)&pbuf[((size_t)ks << 22) + (size_t)b * O_DIM + o];
#pragma unroll
    for (int jj = 0; jj < 4; ++jj) s[jj] += v[jj];
  }
  float gr[E_NUM];
#pragma unroll
  for (int e = 0; e < E_NUM; ++e) gr[e] = g[(size_t)b * E_NUM + e];
#pragma unroll
  for (int e = 0; e < E_NUM; ++e)
#pragma unroll
    for (int jj = 0; jj < 4; ++jj)
      s[jj] += gr[e] * ldany(biasv, (size_t)e * O_DIM + o + jj, isbf);
  if (isbf) {
    ushort4v pk;
#pragma unroll
    for (int jj = 0; jj < 4; ++jj) pk[jj] = f2bf(s[jj]);
    *(ushort4v*)&((unsigned short*)outv)[(size_t)b * O_DIM + o] = pk;
  } else {
    *(f32x4*)&((float*)outv)[(size_t)b * O_DIM + o] = s;
  }
}

extern "C" void kernel_launch(void* const* d_in, const int* in_sizes, int n_in,
                              void* d_out, int out_size, void* d_ws, size_t ws_size,
                              hipStream_t stream) {
  (void)in_sizes; (void)n_in; (void)out_size;
  const void* x    = d_in[0];
  const void* cond = d_in[1];
  const void* w    = d_in[2];
  const void* bias = d_in[3];
  const void* g_w1 = d_in[4];
  const void* g_b1 = d_in[5];
  const void* g_w2 = d_in[6];
  const void* g_b2 = d_in[7];

  const size_t goff  = 1024;
  const size_t wtoff = goff + (size_t)B_ROWS * E_NUM * 4;       // +128KB
  const size_t xboff = wtoff + (size_t)E_NUM * I_DIM * O_DIM * 2; // +16MB
  const size_t poff  = xboff + (size_t)B_ROWS * I_DIM * 2;       // +8MB
  const size_t slab  = (size_t)B_ROWS * O_DIM * 4;               // 16MB

  int KS = 4;
  while (KS > 1 && poff + (size_t)KS * slab > ws_size) KS >>= 1;
  const int EPB = E_NUM / KS;

  int*   flag = (int*)d_ws;
  float* g    = (float*)((char*)d_ws + goff);
  unsigned short* wt = (unsigned short*)((char*)d_ws + wtoff);
  unsigned short* xbb = (unsigned short*)((char*)d_ws + xboff);
  float* pbuf = (float*)((char*)d_ws + poff);

  k_detect<<<1, 64, 0, stream>>>((const unsigned short*)x, flag);
  k_cast_x<<<B_ROWS * I_DIM / 8 / 256, 256, 0, stream>>>(x, flag, xbb);
  k_gating<<<B_ROWS / 256, 256, 0, stream>>>(cond, g_w1, g_b1, g_w2, g_b2, flag, g);
  k_transpose_w<<<E_NUM * 256, 256, 0, stream>>>(w, flag, wt);
  k_moe_gemm<<<KS * MT * NT, 512, 0, stream>>>(xbb, wt, g, pbuf, EPB);
  k_combine<<<B_ROWS * O_DIM / 4 / 256, 256, 0, stream>>>(pbuf, g, bias, flag, d_out, KS);
}

// Round 4
// 161.881 us; speedup vs baseline: 1.5935x; 1.0697x over previous
//
#include <hip/hip_runtime.h>

typedef __attribute__((ext_vector_type(4))) float f32x4;
typedef __attribute__((ext_vector_type(8))) short short8;
typedef __attribute__((ext_vector_type(4))) short short4v;
typedef __attribute__((ext_vector_type(4))) unsigned short ushort4v;
typedef __attribute__((ext_vector_type(8))) unsigned short ushort8v;

#define B_ROWS 4096
#define I_DIM  1024
#define O_DIM  1024
#define C_DIM  128
#define E_NUM  8

__device__ __forceinline__ float bfu2f(unsigned short u) {
  return __uint_as_float(((unsigned int)u) << 16);
}
__device__ __forceinline__ unsigned short f2bf(float f) {
  unsigned int u = __float_as_uint(f);
  unsigned int r = (u + 0x7FFFu + ((u >> 16) & 1u)) >> 16;  // RNE
  return (unsigned short)r;
}
__device__ __forceinline__ float ldany(const void* p, size_t idx, bool isbf) {
  return isbf ? bfu2f(((const unsigned short*)p)[idx]) : ((const float*)p)[idx];
}
__device__ __forceinline__ void gload_lds16(const void* g, void* lds) {
  __builtin_amdgcn_global_load_lds(
      (const __attribute__((address_space(1))) void*)g,
      (__attribute__((address_space(3))) void*)lds, 16, 0, 0);
}

// ---------------- dtype detect: bf16 storage -> flag=1, f32 -> flag=0 -------
__global__ void k_detect(const unsigned short* __restrict__ x, int* __restrict__ flag) {
  if (blockIdx.x == 0 && threadIdx.x == 0) {
    int sane = 0;
    for (int k = 0; k < 128; ++k) {
      const unsigned short v = x[k];
      const int ex = (v >> 7) & 0xFF;
      if (v == 0 || (ex >= 100 && ex <= 132)) ++sane;
    }
    *flag = (sane >= 120) ? 1 : 0;
  }
}

// ---------------- x -> bf16 copy/cast (uniform GEMM input) ------------------
__global__ __launch_bounds__(256) void k_cast_x(
    const void* __restrict__ xv, const int* __restrict__ flag,
    unsigned short* __restrict__ xb)
{
  const bool isbf = (*flag != 0);
  const size_t i = ((size_t)blockIdx.x * 256 + threadIdx.x) * 8;
  if (isbf) {
    *(ushort8v*)&xb[i] = *(const ushort8v*)&((const unsigned short*)xv)[i];
  } else {
    const float* xf = (const float*)xv;
    f32x4 a = *(const f32x4*)&xf[i];
    f32x4 b = *(const f32x4*)&xf[i + 4];
    ushort8v p;
#pragma unroll
    for (int j = 0; j < 4; ++j) { p[j] = f2bf(a[j]); p[j + 4] = f2bf(b[j]); }
    *(ushort8v*)&xb[i] = p;
  }
}

// ---------------- gating MLP + softmax, one thread per row ------------------
__global__ __launch_bounds__(256) void k_gating(
    const void* __restrict__ cond, const void* __restrict__ w1,
    const void* __restrict__ b1, const void* __restrict__ w2,
    const void* __restrict__ b2, const int* __restrict__ flag,
    float* __restrict__ g)
{
  __shared__ float s_w1[C_DIM * 32];
  __shared__ float s_w2[32 * E_NUM];
  __shared__ float s_b1[32];
  __shared__ float s_b2[E_NUM];
  const bool isbf = (*flag != 0);
  for (int t = threadIdx.x; t < C_DIM * 32; t += 256) s_w1[t] = ldany(w1, t, isbf);
  if (threadIdx.x < 32 * E_NUM) s_w2[threadIdx.x] = ldany(w2, threadIdx.x, isbf);
  if (threadIdx.x < 32) s_b1[threadIdx.x] = ldany(b1, threadIdx.x, isbf);
  if (threadIdx.x < E_NUM) s_b2[threadIdx.x] = ldany(b2, threadIdx.x, isbf);
  __syncthreads();
  const int b = blockIdx.x * 256 + threadIdx.x;
  float h[32];
#pragma unroll
  for (int j = 0; j < 32; ++j) h[j] = s_b1[j];
  for (int i = 0; i < C_DIM; i += 8) {
    float c[8];
    if (isbf) {
      const unsigned short* cu = (const unsigned short*)cond;
      ushort8v v = *(const ushort8v*)&cu[(size_t)b * C_DIM + i];
#pragma unroll
      for (int q = 0; q < 8; ++q) c[q] = bfu2f(v[q]);
    } else {
      const float* cf = (const float*)cond;
      f32x4 v0 = *(const f32x4*)&cf[(size_t)b * C_DIM + i];
      f32x4 v1 = *(const f32x4*)&cf[(size_t)b * C_DIM + i + 4];
#pragma unroll
      for (int q = 0; q < 4; ++q) { c[q] = v0[q]; c[q + 4] = v1[q]; }
    }
#pragma unroll
    for (int q = 0; q < 8; ++q)
#pragma unroll
      for (int j = 0; j < 32; ++j)
        h[j] = fmaf(c[q], s_w1[(i + q) * 32 + j], h[j]);
  }
#pragma unroll
  for (int j = 0; j < 32; ++j) h[j] = fmaxf(h[j], 0.f);
  float lg[E_NUM];
#pragma unroll
  for (int e = 0; e < E_NUM; ++e) lg[e] = s_b2[e];
#pragma unroll
  for (int j = 0; j < 32; ++j)
#pragma unroll
    for (int e = 0; e < E_NUM; ++e)
      lg[e] = fmaf(h[j], s_w2[j * E_NUM + e], lg[e]);
  float mx = lg[0];
#pragma unroll
  for (int e = 1; e < E_NUM; ++e) mx = fmaxf(mx, lg[e]);
  float s = 0.f;
#pragma unroll
  for (int e = 0; e < E_NUM; ++e) { lg[e] = expf(lg[e] - mx); s += lg[e]; }
  const float inv = 1.f / s;
#pragma unroll
  for (int e = 0; e < E_NUM; ++e) g[(size_t)b * E_NUM + e] = lg[e] * inv;
}

// ---------------- W[e][i][o] -> Wt[e][o][i] (bf16), 64x64 tiles -------------
// Store phase uses 2x16B stores per thread (was 4x8B scattered).
__global__ __launch_bounds__(256) void k_transpose_w(
    const void* __restrict__ wv, const int* __restrict__ flag,
    unsigned short* __restrict__ wt)
{
  __shared__ float tile[64][65];
  const bool isbf = (*flag != 0);
  const int bid = blockIdx.x;
  const int e = bid >> 8;
  const int t = bid & 255;
  const int i0 = (t >> 4) << 6;
  const int o0 = (t & 15) << 6;
  const size_t base = (size_t)e << 20;
  const int tid = threadIdx.x;
  const int r = tid >> 2;
  const int sub = tid & 3;
  if (isbf) {
    const unsigned short* wu = (const unsigned short*)wv;
#pragma unroll
    for (int q = 0; q < 4; ++q) {
      const int c = sub * 16 + q * 4;
      ushort4v v = *(const ushort4v*)&wu[base + (size_t)(i0 + r) * O_DIM + o0 + c];
#pragma unroll
      for (int j = 0; j < 4; ++j) tile[r][c + j] = bfu2f(v[j]);
    }
  } else {
    const float* wf = (const float*)wv;
#pragma unroll
    for (int q = 0; q < 4; ++q) {
      const int c = sub * 16 + q * 4;
      f32x4 v = *(const f32x4*)&wf[base + (size_t)(i0 + r) * O_DIM + o0 + c];
#pragma unroll
      for (int j = 0; j < 4; ++j) tile[r][c + j] = v[j];
    }
  }
  __syncthreads();
  const int oc  = tid & 63;       // output row (o)
  const int seg = tid >> 6;       // 0..3, 16 i-elements each
  ushort8v p0, p1;
#pragma unroll
  for (int j = 0; j < 8; ++j) p0[j] = f2bf(tile[seg * 16 + j][oc]);
#pragma unroll
  for (int j = 0; j < 8; ++j) p1[j] = f2bf(tile[seg * 16 + 8 + j][oc]);
  unsigned short* dst = &wt[base + (size_t)(o0 + oc) * I_DIM + i0 + seg * 16];
  *(ushort8v*)dst = p0;
  *(ushort8v*)(dst + 8) = p1;
}

// ---------------- main GEMM: register-pipelined ring-3 ----------------------
// 256x256 tile, BK=32, 8 waves (2M x 4N) each 128x64. Iteration t:
//   issue 12 ds_reads for tile t+1 (frag double-buffer) -> MFMA tile t's
//   frags (compiler emits lgkmcnt(12): reads drain DURING MFMA) -> stage
//   tile t+3 into slot t%3 -> vmcnt(4) -> ONE barrier.
// Expert-split-K with gate rescale-chain at expert boundaries.
#define BM 256
#define BN 256
#define BK 32
#define MT (B_ROWS / BM)   // 16
#define NT (O_DIM / BN)    // 4

__global__ __launch_bounds__(512, 2) void k_moe_gemm(
    const unsigned short* __restrict__ xb, const unsigned short* __restrict__ wt,
    const float* __restrict__ g, float* __restrict__ pbuf, int EPB)
{
  __shared__ unsigned short As[3][BM * BK];  // 3 x 16KB, [row][k] 64B rows
  __shared__ unsigned short Bs[3][BN * BK];  // 3 x 16KB, [col][k]
  __shared__ float gsh[BM * E_NUM];          // 8KB

  const int tid  = threadIdx.x;
  const int lane = tid & 63;
  const int w    = tid >> 6;      // wave 0..7
  const int wr   = w >> 2;        // 0..1  (128 rows)
  const int wc   = w & 3;         // 0..3  (64 cols)

  // bijective XCD swizzle (nwg = KS*64, % 8 == 0)
  const int nwg = gridDim.x;
  const int cpx = nwg >> 3;
  const int wg  = ((int)blockIdx.x & 7) * cpx + ((int)blockIdx.x >> 3);
  const int ks  = wg >> 6;            // split-K slice
  const int t2  = wg & 63;
  const int mt  = t2 >> 2;
  const int nt  = t2 & 3;
  const int row0 = mt * BM;
  const int col0 = nt * BN;
  const int NKT  = EPB * (I_DIM / BK);   // tiles per block (pow2)
  const int e0   = ks * EPB;

  for (int i = tid; i < BM * E_NUM; i += 512) gsh[i] = g[row0 * E_NUM + i];

  // staging geometry: wave w covers 32 rows (2 chunks of 16 rows x 32k)
  const int lr = lane >> 2;
  const int ls = lane & 3;
  const unsigned short* aS0 = xb + (size_t)(row0 + w * 32 + lr) * I_DIM + ls * 8;
  const unsigned short* aS1 = aS0 + (size_t)16 * I_DIM;
  const unsigned short* bS0 = wt + (size_t)(col0 + w * 32 + lr) * I_DIM + ls * 8;
  const unsigned short* bS1 = bS0 + (size_t)16 * I_DIM;
  const int dA0 = (w * 2 + 0) * 512, dA1 = (w * 2 + 1) * 512;  // elements

#define STAGE(slot, ebase, koff) do { \
    unsigned short* As_ = (unsigned short*)&As[slot][0]; \
    unsigned short* Bs_ = (unsigned short*)&Bs[slot][0]; \
    gload_lds16(aS0 + (koff), As_ + dA0); \
    gload_lds16(aS1 + (koff), As_ + dA1); \
    gload_lds16(bS0 + (ebase) + (koff), Bs_ + dA0); \
    gload_lds16(bS1 + (ebase) + (koff), Bs_ + dA1); } while (0)

  // fragment read geometry
  const int r16  = lane & 15;
  const int krow = lane >> 4;
  const int aro  = (wr * 128 + r16) * BK + krow * 8;  // + m*512
  const int bro  = (wc * 64 + r16) * BK + krow * 8;   // + n*512

#define READ_FRAGS(fa, fb, slot) do { \
    const unsigned short* Ar_ = &As[slot][0]; \
    const unsigned short* Br_ = &Bs[slot][0]; \
    _Pragma("unroll") for (int n_ = 0; n_ < 4; ++n_) \
      fb[n_] = *(const short8*)&Br_[bro + n_ * 512]; \
    _Pragma("unroll") for (int m_ = 0; m_ < 8; ++m_) \
      fa[m_] = *(const short8*)&Ar_[aro + m_ * 512]; } while (0)

#define MFMA_ALL(fa, fb) do { \
    __builtin_amdgcn_s_setprio(1); \
    _Pragma("unroll") for (int m_ = 0; m_ < 8; ++m_) \
      _Pragma("unroll") for (int n_ = 0; n_ < 4; ++n_) \
        acc[m_][n_] = __builtin_amdgcn_mfma_f32_16x16x32_bf16(fa[m_], fb[n_], acc[m_][n_], 0, 0, 0); \
    __builtin_amdgcn_s_setprio(0); } while (0)

#define RESCALE(en) do { \
    _Pragma("unroll") for (int m_ = 0; m_ < 8; ++m_) { \
      const int rowl_ = wr * 128 + m_ * 16 + krow * 4; \
      float ra_[4]; \
      _Pragma("unroll") for (int r_ = 0; r_ < 4; ++r_) \
        ra_[r_] = fmaxf(gsh[(rowl_ + r_) * E_NUM + (en) - 1], 1e-30f) / \
                  fmaxf(gsh[(rowl_ + r_) * E_NUM + (en)], 1e-30f); \
      _Pragma("unroll") for (int n_ = 0; n_ < 4; ++n_) \
        _Pragma("unroll") for (int r_ = 0; r_ < 4; ++r_) \
          acc[m_][n_][r_] *= ra_[r_]; } } while (0)

  f32x4 acc[8][4];
#pragma unroll
  for (int m = 0; m < 8; ++m)
#pragma unroll
    for (int n = 0; n < 4; ++n)
#pragma unroll
      for (int r2 = 0; r2 < 4; ++r2) acc[m][n][r2] = 0.f;

  short8 a0[8], b0[4], a1[8], b1[4];
  const size_t eb0 = (size_t)e0 << 20;

  // prologue: stage tiles 0,1 -> slots 0,1; read frags(0); stage tile2.
  STAGE(0, eb0, 0);
  STAGE(1, eb0, BK);
  asm volatile("s_waitcnt vmcnt(4)" ::: "memory");   // stage0 done
  __builtin_amdgcn_sched_barrier(0);
  __builtin_amdgcn_s_barrier();
  READ_FRAGS(a0, b0, 0);
  __builtin_amdgcn_sched_barrier(0);
  STAGE(2, eb0, 2 * BK);
  asm volatile("s_waitcnt vmcnt(4)" ::: "memory");   // stage1 done
  __builtin_amdgcn_sched_barrier(0);
  __builtin_amdgcn_s_barrier();

  int srd = 1;  // slot of tile t+1
  int sst = 0;  // slot for tile t+3
  for (int t = 0; t < NKT; t += 2) {
    // ---- even half: read frags(t+1)->(a1,b1), MFMA frags(t)=(a0,b0) ----
    if (t > 0 && (t & 31) == 0) RESCALE(e0 + (t >> 5));
    READ_FRAGS(a1, b1, srd);
    __builtin_amdgcn_sched_barrier(0);
    MFMA_ALL(a0, b0);
    __builtin_amdgcn_sched_barrier(0);
    {
      const int kst = (t + 3) & (NKT - 1);
      STAGE(sst, (size_t)(e0 + (kst >> 5)) << 20, (kst & 31) * BK);
    }
    asm volatile("s_waitcnt vmcnt(4)" ::: "memory");
    __builtin_amdgcn_sched_barrier(0);
    __builtin_amdgcn_s_barrier();
    srd = (srd == 2) ? 0 : srd + 1;
    sst = (sst == 2) ? 0 : sst + 1;

    // ---- odd half: read frags(t+2)->(a0,b0), MFMA frags(t+1)=(a1,b1) ----
    READ_FRAGS(a0, b0, srd);
    __builtin_amdgcn_sched_barrier(0);
    MFMA_ALL(a1, b1);
    __builtin_amdgcn_sched_barrier(0);
    {
      const int kst = (t + 4) & (NKT - 1);
      STAGE(sst, (size_t)(e0 + (kst >> 5)) << 20, (kst & 31) * BK);
    }
    asm volatile("s_waitcnt vmcnt(4)" ::: "memory");
    __builtin_amdgcn_sched_barrier(0);
    __builtin_amdgcn_s_barrier();
    srd = (srd == 2) ? 0 : srd + 1;
    sst = (sst == 2) ? 0 : sst + 1;
  }
#undef STAGE
#undef READ_FRAGS
#undef MFMA_ALL

  // epilogue: drain, final gate scale, write f32 partial
  asm volatile("s_waitcnt vmcnt(0)" ::: "memory");
  const int elast = e0 + EPB - 1;
  float* pb = pbuf + ((size_t)ks << 22);
#pragma unroll
  for (int m = 0; m < 8; ++m) {
    const int rowl = wr * 128 + m * 16 + krow * 4;
    float gl[4];
#pragma unroll
    for (int r2 = 0; r2 < 4; ++r2)
      gl[r2] = fmaxf(gsh[(rowl + r2) * E_NUM + elast], 1e-30f);
#pragma unroll
    for (int n = 0; n < 4; ++n) {
      const int c = col0 + wc * 64 + n * 16 + r16;
#pragma unroll
      for (int r2 = 0; r2 < 4; ++r2)
        pb[(size_t)(row0 + rowl + r2) * O_DIM + c] = acc[m][n][r2] * gl[r2];
    }
  }
}

// ---------------- combine: sum partials + bias term, cast -------------------
__global__ __launch_bounds__(256) void k_combine(
    const float* __restrict__ pbuf, const float* __restrict__ g,
    const void* __restrict__ biasv, const int* __restrict__ flag,
    void* __restrict__ outv, int KS)
{
  const int idx = blockIdx.x * 256 + threadIdx.x;
  const int b = idx >> 8;
  const int o = (idx & 255) << 2;
  const bool isbf = (*flag != 0);
  f32x4 s = {0.f, 0.f, 0.f, 0.f};
  for (int ks = 0; ks < KS; ++ks) {
    f32x4 v = *(const f32x4*)&pbuf[((size_t)ks << 22) + (size_t)b * O_DIM + o];
#pragma unroll
    for (int jj = 0; jj < 4; ++jj) s[jj] += v[jj];
  }
  float gr[E_NUM];
#pragma unroll
  for (int e = 0; e < E_NUM; ++e) gr[e] = g[(size_t)b * E_NUM + e];
#pragma unroll
  for (int e = 0; e < E_NUM; ++e)
#pragma unroll
    for (int jj = 0; jj < 4; ++jj)
      s[jj] += gr[e] * ldany(biasv, (size_t)e * O_DIM + o + jj, isbf);
  if (isbf) {
    ushort4v pk;
#pragma unroll
    for (int jj = 0; jj < 4; ++jj) pk[jj] = f2bf(s[jj]);
    *(ushort4v*)&((unsigned short*)outv)[(size_t)b * O_DIM + o] = pk;
  } else {
    *(f32x4*)&((float*)outv)[(size_t)b * O_DIM + o] = s;
  }
}

extern "C" void kernel_launch(void* const* d_in, const int* in_sizes, int n_in,
                              void* d_out, int out_size, void* d_ws, size_t ws_size,
                              hipStream_t stream) {
  (void)in_sizes; (void)n_in; (void)out_size;
  const void* x    = d_in[0];
  const void* cond = d_in[1];
  const void* w    = d_in[2];
  const void* bias = d_in[3];
  const void* g_w1 = d_in[4];
  const void* g_b1 = d_in[5];
  const void* g_w2 = d_in[6];
  const void* g_b2 = d_in[7];

  const size_t goff  = 1024;
  const size_t wtoff = goff + (size_t)B_ROWS * E_NUM * 4;         // +128KB
  const size_t xboff = wtoff + (size_t)E_NUM * I_DIM * O_DIM * 2; // +16MB
  const size_t poff  = xboff + (size_t)B_ROWS * I_DIM * 2;        // +8MB
  const size_t slab  = (size_t)B_ROWS * O_DIM * 4;                // 16MB

  int KS = 4;
  while (KS > 1 && poff + (size_t)KS * slab > ws_size) KS >>= 1;
  const int EPB = E_NUM / KS;

  int*   flag = (int*)d_ws;
  float* g    = (float*)((char*)d_ws + goff);
  unsigned short* wt = (unsigned short*)((char*)d_ws + wtoff);
  unsigned short* xbb = (unsigned short*)((char*)d_ws + xboff);
  float* pbuf = (float*)((char*)d_ws + poff);

  k_detect<<<1, 64, 0, stream>>>((const unsigned short*)x, flag);
  k_cast_x<<<B_ROWS * I_DIM / 8 / 256, 256, 0, stream>>>(x, flag, xbb);
  k_gating<<<B_ROWS / 256, 256, 0, stream>>>(cond, g_w1, g_b1, g_w2, g_b2, flag, g);
  k_transpose_w<<<E_NUM * 256, 256, 0, stream>>>(w, flag, wt);
  k_moe_gemm<<<KS * MT * NT, 512, 0, stream>>>(xbb, wt, g, pbuf, EPB);
  k_combine<<<B_ROWS * O_DIM / 4 / 256, 256, 0, stream>>>(pbuf, g, bias, flag, d_out, KS);
}